// Round 6
// baseline (2608.037 us; speedup 1.0000x reference)
//
#include <hip/hip_runtime.h>

// x [32,64,64,64] f32, emb [64,1024] f32
// N = 131072 pixels, D = 64, H*W pixels per image plane, K = 1024
// out = [ result: 8388608 f32 ][ argmin-as-f32: 131072 ]
//
// Round 10: R9's math (verified absmax 0.0) with two structural fixes:
//  - vq main loop: counted-vmcnt 4-buffer pipeline (T3/T4). STAGE(t+2)
//    issued 2 iters ahead; s_waitcnt vmcnt(6) steady state (NEVER 0 in
//    the loop); raw s_barrier bracketed by memory-clobber asm so LDS ops
//    can't cross (IntrNoMem barrier hazard). Buffer overwritten at iter
//    t+2 is separated from its iter-t readers by the iter-t+1 barrier
//    plus pre-barrier lgkmcnt(0) -> race-free for all wave pairs.
//    e2 rides in the staged tile (per-lane 4B global_load_lds; all 4
//    waves write identical bytes - benign) so the loop has no un-counted
//    VMEM ops. Full 32-iter unroll (static buffer indices, literal
//    vmcnt). Two acc chains a1/a2 exactly as verified in R8.
//  - prep: 32 blocks x 256 coalesced h/l (c from blockIdx -> lanes are
//    k-contiguous; R5's failure was c in the low bits) + 4 blocks x 256
//    e2 with the bit-identical ascending-d fmaf chain. prep was ~16
//    waves total = the ~50us gap between vq and total in every round.

using half8  = __attribute__((ext_vector_type(8))) _Float16;
using f32x16 = __attribute__((ext_vector_type(16))) float;

__global__ void prep_kernel(const float* __restrict__ emb,
                            float* __restrict__ e2,
                            _Float16* __restrict__ eTh,
                            _Float16* __restrict__ eTl) {
    const int b = blockIdx.x;
    const int t = threadIdx.x;
    if (b < 32) {
        // h/l split: c from block (uniform), k lane-contiguous -> coalesced.
        const int c = b >> 2;                 // 0..7
        const int k = (b & 3) * 256 + t;      // 0..1023
        half8 hv, lv;
#pragma unroll
        for (int j = 0; j < 8; ++j) {
            float v = emb[(c * 8 + j) * 1024 + k];
            _Float16 h = (_Float16)v;          // same split as round 1
            hv[j] = h;
            lv[j] = (_Float16)(v - (float)h);  // exact residual
        }
        *(half8*)(eTh + k * 64 + c * 8) = hv;
        *(half8*)(eTl + k * 64 + c * 8) = lv;
    } else {
        // e2: one thread per k, ascending-d fmaf chain - bit-identical
        // op sequence to the original prep.
        const int k = (b - 32) * 256 + t;
        float s = 0.f;
#pragma unroll
        for (int d = 0; d < 64; ++d) {
            float v = emb[(d << 10) + k];
            s = fmaf(v, v, s);
        }
        e2[k] = s;
    }
}

__launch_bounds__(256, 3)
__global__ void vq_kernel(const float* __restrict__ x,
                          const _Float16* __restrict__ eTh,
                          const _Float16* __restrict__ eTl,
                          const float* __restrict__ e2,
                          const float* __restrict__ emb,
                          float* __restrict__ outq,
                          float* __restrict__ outidx) {
    // per buffer: 4096 halfs B(h|l) = 8KB, then 256B e2 slot -> 4352 halfs
    __shared__ __align__(16) _Float16 sB[4][4352];
    __shared__ int samin[128];

    const int tx = threadIdx.x;
    const int n0 = blockIdx.x * 128;
    const int bb = n0 >> 12;
    const int hw = n0 & 4095;
    const float* xbase = x + bb * 262144 + hw;

    const int lane = tx & 63;
    const int w    = tx >> 6;
    const int c    = lane & 31;    // 32x32 col / A-row
    const int hi   = lane >> 5;    // k-half selector
    const int pxb  = w << 5;       // wave's 32-pixel base

    // ---- A-fragments straight from global (identical values to staged) ----
    half8 ah[4], al[4];
#pragma unroll
    for (int ch = 0; ch < 4; ++ch) {
#pragma unroll
        for (int j = 0; j < 8; ++j) {
            float v = xbase[(ch * 16 + hi * 8 + j) * 4096 + pxb + c];
            _Float16 h = (_Float16)v;
            ah[ch][j] = h;
            al[ch][j] = (_Float16)(v - (float)h);
        }
    }
    asm volatile("" ::: "memory");

    // ---- swizzled LDS read offsets for B (invariant over t) ----------------
    int Dofs[4];
#pragma unroll
    for (int ch = 0; ch < 4; ++ch) {
        const int y = c * 128 + ch * 32 + hi * 16;
        Dofs[ch] = y ^ ((c & 7) << 4);
    }

    // ---- staging sources ---------------------------------------------------
    const int Lb = tx * 16;                        // linear byte in 4KB tile
    const int Sb = Lb ^ (((Lb >> 7) & 7) << 4);    // sigma (self-inverse)
    const char* gH = (const char*)eTh + Sb;
    const char* gL = (const char*)eTl + Sb;
    const char* gE = (const char*)e2 + ((lane & 31) << 2);  // per-lane e2 src

#define STAGE(BUF, TT)                                                        \
    {                                                                         \
        __builtin_amdgcn_global_load_lds(                                     \
            (const __attribute__((address_space(1))) unsigned int*)(gH + ((TT) << 12)), \
            (__attribute__((address_space(3))) unsigned int*)(sB[BUF] + (w << 9)),       \
            16, 0, 0);                                                        \
        __builtin_amdgcn_global_load_lds(                                     \
            (const __attribute__((address_space(1))) unsigned int*)(gL + ((TT) << 12)), \
            (__attribute__((address_space(3))) unsigned int*)(sB[BUF] + 2048 + (w << 9)),\
            16, 0, 0);                                                        \
        __builtin_amdgcn_global_load_lds(                                     \
            (const __attribute__((address_space(1))) unsigned int*)(gE + ((TT) << 7)),  \
            (__attribute__((address_space(3))) unsigned int*)(sB[BUF] + 4096),           \
            4, 0, 0);                                                         \
    }

    float best[16];
    int   bestt[16];
#pragma unroll
    for (int i = 0; i < 16; ++i) { best[i] = 3.4e38f; bestt[i] = 0; }

    // ---- pipelined main loop: 4 buffers, stage-ahead 2, counted vmcnt ------
#define ITER(T, VMSTR)                                                        \
    {                                                                         \
        if ((T) + 2 < 32) STAGE(((T) + 2) & 3, (T) + 2);                      \
        asm volatile("s_waitcnt " VMSTR " lgkmcnt(0)" ::: "memory");          \
        __builtin_amdgcn_s_barrier();                                         \
        asm volatile("" ::: "memory");                                        \
        const char* bbase_ = (const char*)sB[(T) & 3];                        \
        const float e2v_ = *(const float*)(bbase_ + 8192 + (c << 2));         \
        half8 bh_[4], bl_[4];                                                 \
        _Pragma("unroll")                                                     \
        for (int ch = 0; ch < 4; ++ch) {                                      \
            bh_[ch] = *(const half8*)(bbase_ + Dofs[ch]);                     \
            bl_[ch] = *(const half8*)(bbase_ + 4096 + Dofs[ch]);              \
        }                                                                     \
        f32x16 a1 = {};                                                       \
        f32x16 a2 = {};                                                       \
        _Pragma("unroll")                                                     \
        for (int ch = 0; ch < 4; ++ch)                                        \
            a1 = __builtin_amdgcn_mfma_f32_32x32x16_f16(al[ch], bl_[ch], a1, 0, 0, 0); \
        _Pragma("unroll")                                                     \
        for (int ch = 0; ch < 4; ++ch)                                        \
            a1 = __builtin_amdgcn_mfma_f32_32x32x16_f16(al[ch], bh_[ch], a1, 0, 0, 0); \
        _Pragma("unroll")                                                     \
        for (int ch = 0; ch < 4; ++ch)                                        \
            a2 = __builtin_amdgcn_mfma_f32_32x32x16_f16(ah[ch], bl_[ch], a2, 0, 0, 0); \
        _Pragma("unroll")                                                     \
        for (int ch = 0; ch < 4; ++ch)                                        \
            a2 = __builtin_amdgcn_mfma_f32_32x32x16_f16(ah[ch], bh_[ch], a2, 0, 0, 0); \
        _Pragma("unroll")                                                     \
        for (int r = 0; r < 16; ++r) {                                        \
            float dist_ = fmaf(-2.f, a1[r] + a2[r], e2v_);                    \
            if (dist_ < best[r]) { best[r] = dist_; bestt[r] = (T); }         \
        }                                                                     \
    }

    STAGE(0, 0);
    STAGE(1, 1);
    ITER( 0, "vmcnt(6)") ITER( 1, "vmcnt(6)") ITER( 2, "vmcnt(6)")
    ITER( 3, "vmcnt(6)") ITER( 4, "vmcnt(6)") ITER( 5, "vmcnt(6)")
    ITER( 6, "vmcnt(6)") ITER( 7, "vmcnt(6)") ITER( 8, "vmcnt(6)")
    ITER( 9, "vmcnt(6)") ITER(10, "vmcnt(6)") ITER(11, "vmcnt(6)")
    ITER(12, "vmcnt(6)") ITER(13, "vmcnt(6)") ITER(14, "vmcnt(6)")
    ITER(15, "vmcnt(6)") ITER(16, "vmcnt(6)") ITER(17, "vmcnt(6)")
    ITER(18, "vmcnt(6)") ITER(19, "vmcnt(6)") ITER(20, "vmcnt(6)")
    ITER(21, "vmcnt(6)") ITER(22, "vmcnt(6)") ITER(23, "vmcnt(6)")
    ITER(24, "vmcnt(6)") ITER(25, "vmcnt(6)") ITER(26, "vmcnt(6)")
    ITER(27, "vmcnt(6)") ITER(28, "vmcnt(6)") ITER(29, "vmcnt(6)")
    ITER(30, "vmcnt(3)") ITER(31, "vmcnt(0)")

    // ---- per-pixel argmin: butterfly over the 32 cols (lanes) --------------
    // k = t*32 + c; ascending-t strict < kept earliest k per lane; cross-lane
    // merge breaks ties toward smaller k. C layout (verified m74/m101):
    // col = lane&31, row = (r&3) + 8*(r>>2) + 4*hi.
#pragma unroll
    for (int r = 0; r < 16; ++r) {
        float bv = best[r];
        int   bk = (bestt[r] << 5) + c;
#pragma unroll
        for (int m = 1; m < 32; m <<= 1) {
            float ov = __shfl_xor(bv, m, 64);
            int   ok = __shfl_xor(bk, m, 64);
            if (ov < bv || (ov == bv && ok < bk)) { bv = ov; bk = ok; }
        }
        if (c == 0) {
            const int row = (r & 3) + 8 * (r >> 2) + 4 * hi;
            samin[pxb + row] = bk;
        }
    }
    __syncthreads();

    if (tx < 128) outidx[n0 + tx] = (float)samin[tx];

    // ---- gather exact fp32 codebook rows -> output, coalesced over p -------
    const int p = tx & 127;
    const int drow = tx >> 7;                 // 0 or 1
    const int amin = samin[p];
    float* obase = outq + bb * 262144 + hw + p;
#pragma unroll
    for (int it = 0; it < 32; ++it) {
        int d = (it << 1) + drow;
        obase[d * 4096] = emb[d * 1024 + amin];
    }
}

extern "C" void kernel_launch(void* const* d_in, const int* in_sizes, int n_in,
                              void* d_out, int out_size, void* d_ws, size_t ws_size,
                              hipStream_t stream) {
    const float* x   = (const float*)d_in[0];
    const float* emb = (const float*)d_in[1];
    float* outq   = (float*)d_out;
    float* outidx = outq + 8388608;            // 32*64*64*64

    float*    e2  = (float*)d_ws;                               // 4 KB
    _Float16* eTh = (_Float16*)((char*)d_ws + 4096);            // 128 KB
    _Float16* eTl = (_Float16*)((char*)d_ws + 4096 + 131072);   // 128 KB

    prep_kernel<<<36, 256, 0, stream>>>(emb, e2, eTh, eTl);
    vq_kernel<<<1024, 256, 0, stream>>>(x, eTh, eTl, e2, emb, outq, outidx);
}

// Round 7
// 290.299 us; speedup vs baseline: 8.9840x; 8.9840x over previous
//
#include <hip/hip_runtime.h>

// x [32,64,64,64] f32, emb [64,1024] f32
// N = 131072 pixels, D = 64, K = 1024
// out = [ result: 8388608 f32 ][ argmin-as-f32: 131072 ]
//
// Round 11: R10's counted-vmcnt pipeline logic (correctness-proven there:
// absmax 0.0) re-expressed so regalloc survives:
//  - R10 failed via SCRATCH (FETCH 7GB, VGPR 84, 32KB/thread spill): the
//    full 32-body macro unroll made one giant scheduling region. Fix:
//    '#pragma unroll 1' loop over t+=4 with FOUR static-buffer bodies
//    (t==0 mod 4 -> buf ids are literals), peeled 4-body tail for the
//    vmcnt taper 6/6/3/0. Only one body's transients live at a time.
//  - single chained f32x16 accumulator (R9-verified bit-identical) so the
//    wave fits <=128 regs -> __launch_bounds__(256,4) = 4 blocks/CU,
//    exactly matching the 1024-block grid.
//  - pipeline invariants (unchanged from R10): 4 buffers, STAGE(T+2)
//    issued 2 ahead, s_waitcnt vmcnt(6) lgkmcnt(0) BEFORE s_barrier
//    (never 0 in steady state), sched_barrier(0) after (rule #18).
//    Write-after-read safe: buf overwritten at body T was read at body
//    T-2, separated by the body T-1 barrier; per-wave vmcnt waits before
//    the barrier make all waves' slices visible after it.
//  - e2 rides in the staged tile (3rd global_load_lds, counted) so the
//    loop has ZERO uncounted VMEM ops.
//  - prep: R10's 36x256 parallel version (correctness-proven).

using half8  = __attribute__((ext_vector_type(8))) _Float16;
using f32x16 = __attribute__((ext_vector_type(16))) float;

__global__ void prep_kernel(const float* __restrict__ emb,
                            float* __restrict__ e2,
                            _Float16* __restrict__ eTh,
                            _Float16* __restrict__ eTl) {
    const int b = blockIdx.x;
    const int t = threadIdx.x;
    if (b < 32) {
        // h/l split: c from block (uniform), k lane-contiguous -> coalesced.
        const int c = b >> 2;                 // 0..7
        const int k = (b & 3) * 256 + t;      // 0..1023
        half8 hv, lv;
#pragma unroll
        for (int j = 0; j < 8; ++j) {
            float v = emb[(c * 8 + j) * 1024 + k];
            _Float16 h = (_Float16)v;          // same split as round 1
            hv[j] = h;
            lv[j] = (_Float16)(v - (float)h);  // exact residual
        }
        *(half8*)(eTh + k * 64 + c * 8) = hv;
        *(half8*)(eTl + k * 64 + c * 8) = lv;
    } else {
        // e2: one thread per k, ascending-d fmaf chain - bit-identical
        // op sequence to the original prep.
        const int k = (b - 32) * 256 + t;
        float s = 0.f;
#pragma unroll
        for (int d = 0; d < 64; ++d) {
            float v = emb[(d << 10) + k];
            s = fmaf(v, v, s);
        }
        e2[k] = s;
    }
}

__launch_bounds__(256, 4)
__global__ void vq_kernel(const float* __restrict__ x,
                          const _Float16* __restrict__ eTh,
                          const _Float16* __restrict__ eTl,
                          const float* __restrict__ e2,
                          const float* __restrict__ emb,
                          float* __restrict__ outq,
                          float* __restrict__ outidx) {
    // per buffer: 4096 halfs B(h|l) = 8KB, then e2 slot -> 4352 halfs
    __shared__ __align__(16) _Float16 sB[4][4352];
    __shared__ int samin[128];

    const int tx = threadIdx.x;
    const int n0 = blockIdx.x * 128;
    const int bb = n0 >> 12;
    const int hw = n0 & 4095;
    const float* xbase = x + bb * 262144 + hw;

    const int lane = tx & 63;
    const int w    = tx >> 6;
    const int c    = lane & 31;    // 32x32 col / A-row
    const int hi   = lane >> 5;    // k-half selector
    const int pxb  = w << 5;       // wave's 32-pixel base

    // ---- A-fragments straight from global (identical values to staged) ----
    half8 ah[4], al[4];
#pragma unroll
    for (int ch = 0; ch < 4; ++ch) {
#pragma unroll
        for (int j = 0; j < 8; ++j) {
            float v = xbase[(ch * 16 + hi * 8 + j) * 4096 + pxb + c];
            _Float16 h = (_Float16)v;
            ah[ch][j] = h;
            al[ch][j] = (_Float16)(v - (float)h);
        }
    }
    asm volatile("" ::: "memory");   // A-loads consumed before staging begins

    // ---- swizzled LDS read offsets for B (invariant over t) ----------------
    int Dofs[4];
#pragma unroll
    for (int ch = 0; ch < 4; ++ch) {
        const int y = c * 128 + ch * 32 + hi * 16;
        Dofs[ch] = y ^ ((c & 7) << 4);
    }

    // ---- staging sources ---------------------------------------------------
    const int Lb = tx * 16;                        // linear byte in 4KB tile
    const int Sb = Lb ^ (((Lb >> 7) & 7) << 4);    // sigma (self-inverse)
    const char* gH = (const char*)eTh + Sb;
    const char* gL = (const char*)eTl + Sb;
    const char* gE = (const char*)e2 + ((lane & 31) << 2);  // per-lane e2 src

#define STAGE(BUF, TT)                                                        \
    {                                                                         \
        __builtin_amdgcn_global_load_lds(                                     \
            (const __attribute__((address_space(1))) unsigned int*)(gH + ((TT) << 12)), \
            (__attribute__((address_space(3))) unsigned int*)(sB[BUF] + (w << 9)),       \
            16, 0, 0);                                                        \
        __builtin_amdgcn_global_load_lds(                                     \
            (const __attribute__((address_space(1))) unsigned int*)(gL + ((TT) << 12)), \
            (__attribute__((address_space(3))) unsigned int*)(sB[BUF] + 2048 + (w << 9)),\
            16, 0, 0);                                                        \
        __builtin_amdgcn_global_load_lds(                                     \
            (const __attribute__((address_space(1))) unsigned int*)(gE + ((TT) << 7)),  \
            (__attribute__((address_space(3))) unsigned int*)(sB[BUF] + 4096),           \
            4, 0, 0);                                                         \
    }

#define WAITBAR(VMSTR)                                                        \
    asm volatile("s_waitcnt " VMSTR " lgkmcnt(0)" ::: "memory");              \
    __builtin_amdgcn_s_barrier();                                             \
    __builtin_amdgcn_sched_barrier(0);

#define COMPUTE(BUF, TT)                                                      \
    {                                                                         \
        const char* bbase_ = (const char*)sB[BUF];                            \
        const float e2v_ = *(const float*)(bbase_ + 8192 + (c << 2));         \
        half8 bh_[4], bl_[4];                                                 \
        _Pragma("unroll")                                                     \
        for (int ch = 0; ch < 4; ++ch) {                                      \
            bh_[ch] = *(const half8*)(bbase_ + Dofs[ch]);                     \
            bl_[ch] = *(const half8*)(bbase_ + 4096 + Dofs[ch]);              \
        }                                                                     \
        f32x16 a = {};                                                        \
        _Pragma("unroll")                                                     \
        for (int ch = 0; ch < 4; ++ch)                                        \
            a = __builtin_amdgcn_mfma_f32_32x32x16_f16(al[ch], bl_[ch], a, 0, 0, 0); \
        _Pragma("unroll")                                                     \
        for (int ch = 0; ch < 4; ++ch)                                        \
            a = __builtin_amdgcn_mfma_f32_32x32x16_f16(al[ch], bh_[ch], a, 0, 0, 0); \
        _Pragma("unroll")                                                     \
        for (int ch = 0; ch < 4; ++ch)                                        \
            a = __builtin_amdgcn_mfma_f32_32x32x16_f16(ah[ch], bl_[ch], a, 0, 0, 0); \
        _Pragma("unroll")                                                     \
        for (int ch = 0; ch < 4; ++ch)                                        \
            a = __builtin_amdgcn_mfma_f32_32x32x16_f16(ah[ch], bh_[ch], a, 0, 0, 0); \
        _Pragma("unroll")                                                     \
        for (int r = 0; r < 16; ++r) {                                        \
            float dist_ = fmaf(-2.f, a[r], e2v_);                             \
            if (dist_ < best[r]) { best[r] = dist_; bestt[r] = (TT); }        \
        }                                                                     \
    }

    float best[16];
    int   bestt[16];
#pragma unroll
    for (int i = 0; i < 16; ++i) { best[i] = 3.4e38f; bestt[i] = 0; }

    // ---- 4-buffer, stage-ahead-2, counted-vmcnt pipeline -------------------
    STAGE(0, 0);
    STAGE(1, 1);
#pragma unroll 1
    for (int t = 0; t < 28; t += 4) {
        STAGE(2, t + 2); WAITBAR("vmcnt(6)") COMPUTE(0, t + 0)
        STAGE(3, t + 3); WAITBAR("vmcnt(6)") COMPUTE(1, t + 1)
        STAGE(0, t + 4); WAITBAR("vmcnt(6)") COMPUTE(2, t + 2)
        STAGE(1, t + 5); WAITBAR("vmcnt(6)") COMPUTE(3, t + 3)
    }
    // tail: T = 28..31 (no more stages after T=31)
    STAGE(2, 30); WAITBAR("vmcnt(6)") COMPUTE(0, 28)
    STAGE(3, 31); WAITBAR("vmcnt(6)") COMPUTE(1, 29)
    WAITBAR("vmcnt(3)") COMPUTE(2, 30)
    WAITBAR("vmcnt(0)") COMPUTE(3, 31)

    // ---- per-pixel argmin: butterfly over the 32 cols (lanes) --------------
    // k = t*32 + c; ascending-t strict < kept earliest k per lane; cross-lane
    // merge breaks ties toward smaller k. C layout (verified m74/m101):
    // col = lane&31, row = (r&3) + 8*(r>>2) + 4*hi.
#pragma unroll
    for (int r = 0; r < 16; ++r) {
        float bv = best[r];
        int   bk = (bestt[r] << 5) + c;
#pragma unroll
        for (int m = 1; m < 32; m <<= 1) {
            float ov = __shfl_xor(bv, m, 64);
            int   ok = __shfl_xor(bk, m, 64);
            if (ov < bv || (ov == bv && ok < bk)) { bv = ov; bk = ok; }
        }
        if (c == 0) {
            const int row = (r & 3) + 8 * (r >> 2) + 4 * hi;
            samin[pxb + row] = bk;
        }
    }
    __syncthreads();

    if (tx < 128) outidx[n0 + tx] = (float)samin[tx];

    // ---- gather exact fp32 codebook rows -> output, coalesced over p -------
    const int p = tx & 127;
    const int drow = tx >> 7;                 // 0 or 1
    const int amin = samin[p];
    float* obase = outq + bb * 262144 + hw + p;
#pragma unroll
    for (int it = 0; it < 32; ++it) {
        int d = (it << 1) + drow;
        obase[d * 4096] = emb[d * 1024 + amin];
    }
}

extern "C" void kernel_launch(void* const* d_in, const int* in_sizes, int n_in,
                              void* d_out, int out_size, void* d_ws, size_t ws_size,
                              hipStream_t stream) {
    const float* x   = (const float*)d_in[0];
    const float* emb = (const float*)d_in[1];
    float* outq   = (float*)d_out;
    float* outidx = outq + 8388608;            // 32*64*64*64

    float*    e2  = (float*)d_ws;                               // 4 KB
    _Float16* eTh = (_Float16*)((char*)d_ws + 4096);            // 128 KB
    _Float16* eTl = (_Float16*)((char*)d_ws + 4096 + 131072);   // 128 KB

    prep_kernel<<<36, 256, 0, stream>>>(emb, e2, eTh, eTl);
    vq_kernel<<<1024, 256, 0, stream>>>(x, eTh, eTl, e2, emb, outq, outidx);
}